// Round 10
// baseline (333.051 us; speedup 1.0000x reference)
//
#include <hip/hip_runtime.h>
#include <hip/hip_fp16.h>
#include <math.h>

// Problem constants (match reference)
constexpr int N_NODES = 65536;
constexpr int N_EDGES = 2097152;
constexpr int F_IN    = 128;
constexpr int H_DIM   = 256;
constexpr int O_DIM   = 128;
constexpr int N_GRAPH = 256;
constexpr int V_SIZE  = 1000;

// 256 buckets of 256 nodes (bucket = col>>8); 512 edge-blocks of 4096 edges.
constexpr int EPB  = 4096;
constexpr int NBLK = N_EDGES / EPB;   // 512

typedef _Float16 half8 __attribute__((ext_vector_type(8)));
typedef float floatx4 __attribute__((ext_vector_type(4)));

// ---------------- init: pool=0, graph counts, cfW1 table, W2T fp16 ----------

__global__ void k_init(float* __restrict__ pool, const int* __restrict__ batch,
                       float* __restrict__ cntf, const float* __restrict__ cf,
                       const float* __restrict__ W1, __half* __restrict__ cfW1,
                       const float* __restrict__ W2, _Float16* __restrict__ W2T) {
    __shared__ float xs[8 * F_IN];    // 4 KB
    int i = blockIdx.x * blockDim.x + threadIdx.x;
    if (i < N_GRAPH * O_DIM) pool[i] = 0.0f;
    if (blockIdx.x == 0) {
        // batch_index sorted: per-graph counts via binary search, no atomics
        int g = threadIdx.x;
        int lo = 0, hi = N_NODES;
        while (lo < hi) { int m = (lo + hi) >> 1; if (batch[m] < g) lo = m + 1; else hi = m; }
        int start = lo;
        lo = 0; hi = N_NODES;
        while (lo < hi) { int m = (lo + hi) >> 1; if (batch[m] <= g) lo = m + 1; else hi = m; }
        cntf[g] = (float)(lo - start);
    }
    if (blockIdx.x < V_SIZE / 8) {    // 125 blocks compute the cfW1 table
        int rb = blockIdx.x * 8;
        int t  = threadIdx.x;
        #pragma unroll
        for (int p = 0; p < 4; ++p) {
            int idx = p * 256 + t;
            int r = idx >> 7, k = idx & 127;
            xs[idx] = cf[(size_t)(rb + r) * F_IN + k];
        }
        __syncthreads();
        float acc[8] = {};
        for (int k = 0; k < F_IN; ++k) {
            float w = W1[k * H_DIM + t];
            #pragma unroll
            for (int j = 0; j < 8; ++j) acc[j] += xs[j * F_IN + k] * w;
        }
        #pragma unroll
        for (int j = 0; j < 8; ++j)
            cfW1[(size_t)(rb + j) * H_DIM + t] = __float2half(acc[j]);
    }
    if (blockIdx.x >= 128) {          // 128 blocks: W2T transpose fp32->fp16
        int idx = (blockIdx.x - 128) * 256 + threadIdx.x;   // 0..32767
        int nn = idx >> 8, kk = idx & 255;
        W2T[idx] = (_Float16)W2[kk * O_DIM + nn];
    }
}

// ---------------- stage A: per-block bucket histogram (512 blocks x 1024) ---

__global__ void k_hist(const int* __restrict__ col, int* __restrict__ hist) {
    __shared__ int h[256];
    int t = threadIdx.x;
    if (t < 256) h[t] = 0;
    __syncthreads();
    int base = blockIdx.x * EPB;
    #pragma unroll
    for (int i = 0; i < EPB / 1024; ++i)
        atomicAdd(&h[col[base + i * 1024 + t] >> 8], 1);
    __syncthreads();
    if (t < 256) hist[t * NBLK + blockIdx.x] = h[t];   // bucket-major for the scan
}

// ---------------- scan (partial per-256-chunk + block sums) ----------------
// scans the 131072-entry bucket-major histogram; 512 chunk sums in bsum.

__global__ void k_scan1(const int* __restrict__ in, int* __restrict__ out,
                        int* __restrict__ bsum) {
    __shared__ int s[256];
    int tid = threadIdx.x;
    int i = blockIdx.x * 256 + tid;
    int v = in[i];
    s[tid] = v;
    __syncthreads();
    for (int d = 1; d < 256; d <<= 1) {
        int t = (tid >= d) ? s[tid - d] : 0;
        __syncthreads();
        s[tid] += t;
        __syncthreads();
    }
    out[i] = s[tid] - v;
    if (tid == 255) bsum[blockIdx.x] = s[255];
}

// 512-entry block-sum scan: 256 threads x 2 items each
__global__ void k_scan2(int* __restrict__ bsum) {
    __shared__ int s[256];
    int t = threadIdx.x;
    int2 v = *(int2*)&bsum[2 * t];
    int tsum = v.x + v.y;
    s[t] = tsum;
    __syncthreads();
    for (int d = 1; d < 256; d <<= 1) {
        int x = (t >= d) ? s[t - d] : 0;
        __syncthreads();
        s[t] += x;
        __syncthreads();
    }
    int ex = s[t] - tsum;
    bsum[2 * t]     = ex;
    bsum[2 * t + 1] = ex + v.x;
}

// ---------------- stage C: partition into int2 records (512 blocks x 1024) --
// rec.x = src:16 | dst8:8 | vocab_hi:8 ; rec.y = vocab_lo:2<<16 | ew_fp16:16

__global__ void k_part(const int* __restrict__ row, const int* __restrict__ col,
                       const float* __restrict__ ew, const int* __restrict__ nidx,
                       const int* __restrict__ hoffs, const int* __restrict__ bsum,
                       int2* __restrict__ part) {
    __shared__ int cur[256];
    int t = threadIdx.x;
    if (t < 256) {
        int idx = t * NBLK + blockIdx.x;
        cur[t] = hoffs[idx] + bsum[idx >> 8];
    }
    __syncthreads();
    int base = blockIdx.x * EPB;
    #pragma unroll
    for (int i = 0; i < EPB / 1024; ++i) {
        int e = base + i * 1024 + t;
        int r = row[e], c = col[e];
        unsigned hw = (unsigned)__half_as_ushort(__float2half(ew[e]));
        int vb = nidx[r];
        int slot = atomicAdd(&cur[c >> 8], 1);
        int2 rec;
        rec.x = (r << 16) | ((c & 255) << 8) | (vb >> 2);
        rec.y = (int)(((unsigned)(vb & 3) << 16) | hw);
        part[slot] = rec;
    }
}

// ---------------- stage D1: per-(bucket,q) degree accumulate ----------------
// 1024 blocks = q*256 + bucket (q-siblings share an XCD since 256%8==0).
// Block scans its bucket's whole segment, accumulates only dst in [q*64,q*64+64):
// packed u32 = count:8 | wsum_fxp16:24 (w<=1.0, deg<=255 -> no overflow).

__global__ void k_degq(const int* __restrict__ hoffs, const int* __restrict__ bsum,
                       const int2* __restrict__ part, unsigned* __restrict__ dcq) {
    __shared__ unsigned dc[64];
    int t = threadIdx.x;
    int bucket = blockIdx.x & 255, q = blockIdx.x >> 8;
    if (t < 64) dc[t] = 0u;
    __syncthreads();
    int start = hoffs[bucket * NBLK] + bsum[bucket * 2];
    int end   = (bucket == 255) ? N_EDGES
                                : (hoffs[(bucket + 1) * NBLK] + bsum[(bucket + 1) * 2]);
    for (int j = start + t; j < end; j += 1024) {
        int2 rec = part[j];
        int dst = (rec.x >> 8) & 255;
        if ((dst >> 6) == q) {
            float w = __half2float(__ushort_as_half((unsigned short)(rec.y & 0xFFFF)));
            atomicAdd(&dc[dst & 63], (1u << 24) | (unsigned)(w * 65536.0f + 0.5f));
        }
    }
    __syncthreads();
    if (t < 64) dcq[bucket * 256 + q * 64 + t] = dc[t];
}

// ---------------- stage D1b: dis + per-dst CSR offsets ----------------------

__global__ void k_disoffs(const unsigned* __restrict__ dcq,
                          const int* __restrict__ hoffs, const int* __restrict__ bsum,
                          float* __restrict__ dis, int* __restrict__ offs) {
    __shared__ int sc[256];
    int t = threadIdx.x;
    int bucket = blockIdx.x;
    unsigned v = dcq[bucket * 256 + t];
    float wsum = (float)(v & 0xFFFFFFu) * (1.0f / 65536.0f);
    float deg = 1.0f + wsum;                    // self-loop +1
    dis[bucket * 256 + t] = 1.0f / sqrtf(deg);  // deg >= 1
    int cnt = (int)(v >> 24);
    int bstart = hoffs[bucket * NBLK] + bsum[bucket * 2];
    sc[t] = cnt;
    __syncthreads();
    for (int d = 1; d < 256; d <<= 1) {
        int x = (t >= d) ? sc[t - d] : 0;
        __syncthreads();
        sc[t] += x;
        __syncthreads();
    }
    offs[bucket * 256 + t] = bstart + sc[t] - cnt;
    if (bucket == 255 && t == 255) offs[N_NODES] = N_EDGES;
}

// ---------------- stage D2: scatter to final CSR, q-split -------------------
// 1024 blocks = q*256 + bucket; block-private LDS cursors for its 64 dsts.
// csr.x = src<<10 | vocab ; csr.y = dis[src] * ew (dis[dst] applied in agg).

__global__ void k_build2q(const int* __restrict__ hoffs, const int* __restrict__ bsum,
                          const int2* __restrict__ part, const float* __restrict__ dis,
                          const int* __restrict__ offs, int2* __restrict__ csr) {
    __shared__ int cur[64];
    int t = threadIdx.x;
    int bucket = blockIdx.x & 255, q = blockIdx.x >> 8;
    if (t < 64) cur[t] = offs[bucket * 256 + q * 64 + t];
    __syncthreads();
    int start = hoffs[bucket * NBLK] + bsum[bucket * 2];
    int end   = (bucket == 255) ? N_EDGES
                                : (hoffs[(bucket + 1) * NBLK] + bsum[(bucket + 1) * 2]);
    for (int j = start + t; j < end; j += 1024) {
        int2 rec = part[j];
        int dst = (rec.x >> 8) & 255;
        if ((dst >> 6) == q) {
            unsigned src = ((unsigned)rec.x) >> 16;
            int vb = ((rec.x & 255) << 2) | ((rec.y >> 16) & 3);
            float w = __half2float(__ushort_as_half((unsigned short)(rec.y & 0xFFFF)));
            float nm = dis[src] * w;
            int slot = atomicAdd(&cur[dst & 63], 1);
            int2 e;
            e.x = (int)((src << 10) | (unsigned)vb);
            e.y = __float_as_int(nm);
            csr[slot] = e;
        }
    }
}

// 8-half fp16 row-fragment accumulate: e[k] += f32(v[k]) * n
__device__ __forceinline__ void acc8(float* e, int4 v, float n) {
    float2 f0 = __half22float2(*(__half2*)&v.x);
    float2 f1 = __half22float2(*(__half2*)&v.y);
    float2 f2 = __half22float2(*(__half2*)&v.z);
    float2 f3 = __half22float2(*(__half2*)&v.w);
    e[0] += f0.x * n; e[1] += f0.y * n;
    e[2] += f1.x * n; e[3] += f1.y * n;
    e[4] += f2.x * n; e[5] += f2.y * n;
    e[6] += f3.x * n; e[7] += f3.y * n;
}

// ---------------- layer-1: gather-aggregate cfW1 rows -> h1 (R1-exact) ------

__global__ void k_agg1(const int4* __restrict__ cfW1, const int* __restrict__ nidx,
                       const float* __restrict__ dis, const int* __restrict__ offs,
                       const int2* __restrict__ csr, const float4* __restrict__ b1f4,
                       int4* __restrict__ h1) {
    int wave = threadIdx.x >> 6;
    int lane = threadIdx.x & 63;
    int g    = lane >> 5;        // which edge of the pair
    int sl   = lane & 31;        // int4 slot within the 256-half row
    int c = blockIdx.x * 4 + wave;
    float d = dis[c];
    int4 sp = cfW1[(size_t)nidx[c] * 32 + sl];
    float esum[8] = {0.f, 0.f, 0.f, 0.f, 0.f, 0.f, 0.f, 0.f};
    int a0 = offs[c], a1 = offs[c + 1];
    int s = a0;
    // peel one edge if start is odd (keeps scalar int4 loads 16B-aligned)
    if (s < a1 && (s & 1)) {
        int sb = __builtin_amdgcn_readfirstlane(s);
        int2 e0 = csr[sb];
        int4 v0 = cfW1[(size_t)(e0.x & 1023) * 32 + sl];
        float n = (g == 0) ? __int_as_float(e0.y) : 0.0f;
        acc8(esum, v0, n);
        ++s;
    }
    // main: 4 pairs (8 edges) per batch, 4 int4 gathers in flight
    for (; s + 8 <= a1; s += 8) {
        int sb = __builtin_amdgcn_readfirstlane(s);
        int4 ee[4];
        #pragma unroll
        for (int u = 0; u < 4; ++u) ee[u] = *(const int4*)(csr + sb + 2 * u);
        int4 v[4]; float n[4];
        #pragma unroll
        for (int u = 0; u < 4; ++u) {
            int ex = g ? ee[u].z : ee[u].x;
            int ey = g ? ee[u].w : ee[u].y;
            n[u] = __int_as_float(ey);
            v[u] = cfW1[(size_t)(ex & 1023) * 32 + sl];
        }
        #pragma unroll
        for (int u = 0; u < 4; ++u) acc8(esum, v[u], n[u]);
    }
    // pair tail
    for (; s + 2 <= a1; s += 2) {
        int sb = __builtin_amdgcn_readfirstlane(s);
        int4 ee = *(const int4*)(csr + sb);
        int ex = g ? ee.z : ee.x;
        int ey = g ? ee.w : ee.y;
        int4 v0 = cfW1[(size_t)(ex & 1023) * 32 + sl];
        acc8(esum, v0, __int_as_float(ey));
    }
    // single tail
    if (s < a1) {
        int sb = __builtin_amdgcn_readfirstlane(s);
        int2 e0 = csr[sb];
        int4 v0 = cfW1[(size_t)(e0.x & 1023) * 32 + sl];
        float n = (g == 0) ? __int_as_float(e0.y) : 0.0f;
        acc8(esum, v0, n);
    }
    // combine the two half-wave partial sums
    #pragma unroll
    for (int k = 0; k < 8; ++k) esum[k] += __shfl_xor(esum[k], 32, 64);

    float dd = d * d;
    float2 s0 = __half22float2(*(__half2*)&sp.x);
    float2 s1 = __half22float2(*(__half2*)&sp.y);
    float2 s2 = __half22float2(*(__half2*)&sp.z);
    float2 s3 = __half22float2(*(__half2*)&sp.w);
    float4 bb0 = b1f4[2 * sl];
    float4 bb1 = b1f4[2 * sl + 1];
    float r[8];
    r[0] = bb0.x + s0.x * dd + d * esum[0];
    r[1] = bb0.y + s0.y * dd + d * esum[1];
    r[2] = bb0.z + s1.x * dd + d * esum[2];
    r[3] = bb0.w + s1.y * dd + d * esum[3];
    r[4] = bb1.x + s2.x * dd + d * esum[4];
    r[5] = bb1.y + s2.y * dd + d * esum[5];
    r[6] = bb1.z + s3.x * dd + d * esum[6];
    r[7] = bb1.w + s3.y * dd + d * esum[7];
    #pragma unroll
    for (int k = 0; k < 8; ++k) r[k] = r[k] > 0.f ? r[k] : 0.f;
    float2 p0 = {r[0], r[1]}, p1 = {r[2], r[3]}, p2 = {r[4], r[5]}, p3 = {r[6], r[7]};
    __half2 h0 = __float22half2_rn(p0);
    __half2 h1v = __float22half2_rn(p1);
    __half2 h2 = __float22half2_rn(p2);
    __half2 h3 = __float22half2_rn(p3);
    int4 outv;
    outv.x = *(int*)&h0;
    outv.y = *(int*)&h1v;
    outv.z = *(int*)&h2;
    outv.w = *(int*)&h3;
    if (lane < 32) h1[(size_t)c * 32 + sl] = outv;
}

// ---------------- GEMM2 via MFMA: h1 [N,256] fp16 @ W2 -> xw2h fp16 ---------

__global__ void k_gemm2(const _Float16* __restrict__ h1, const _Float16* __restrict__ W2T,
                        __half* __restrict__ xw2h) {
    int wave = threadIdx.x >> 6;
    int lane = threadIdx.x & 63;
    int quad = lane >> 4;
    int n    = lane & 15;
    int tm   = blockIdx.x * 4 + wave;                  // 16-row tile index
    const _Float16* arow = h1 + (size_t)(tm * 16 + n) * H_DIM;
    half8 a[8];
    #pragma unroll
    for (int kt = 0; kt < 8; ++kt)
        a[kt] = *(const half8*)(arow + kt * 32 + quad * 8);
    #pragma unroll
    for (int nt = 0; nt < 8; ++nt) {
        floatx4 acc = {0.f, 0.f, 0.f, 0.f};
        const _Float16* brow = W2T + (size_t)(nt * 16 + n) * H_DIM;
        #pragma unroll
        for (int kt = 0; kt < 8; ++kt) {
            half8 b = *(const half8*)(brow + kt * 32 + quad * 8);
            acc = __builtin_amdgcn_mfma_f32_16x16x32_f16(a[kt], b, acc, 0, 0, 0);
        }
        #pragma unroll
        for (int r = 0; r < 4; ++r) {
            int rowi = tm * 16 + quad * 4 + r;
            xw2h[(size_t)rowi * O_DIM + nt * 16 + n] = __float2half(acc[r]);
        }
    }
}

// ---------------- layer-2 agg + relu + LDS-reduced pool (R1-exact) ----------

__global__ void k_agg2_pool(const int4* __restrict__ xw2h, const float* __restrict__ b2,
                            const float* __restrict__ dis, const int* __restrict__ offs,
                            const int2* __restrict__ csr, const int* __restrict__ batch,
                            float* __restrict__ pool) {
    __shared__ float red[4][128];
    __shared__ int bgs[4];
    int wave = threadIdx.x >> 6;
    int lane = threadIdx.x & 63;
    int grp  = lane >> 4;        // which edge of the quad
    int sl   = lane & 15;        // int4 slot within the 128-half row
    int c = blockIdx.x * 4 + wave;
    float d = dis[c];
    int4 sp = xw2h[(size_t)c * 16 + sl];
    float esum[8] = {0.f, 0.f, 0.f, 0.f, 0.f, 0.f, 0.f, 0.f};
    int s0 = offs[c], s1 = offs[c + 1];
    int s = s0;
    // main: 4 quads (16 edges) per batch, 4 int4 gathers in flight
    for (; s + 16 <= s1; s += 16) {
        int sb = __builtin_amdgcn_readfirstlane(s);
        int2 e[4];
        #pragma unroll
        for (int u = 0; u < 4; ++u) e[u] = csr[sb + 4 * u + grp];
        int4 v[4];
        #pragma unroll
        for (int u = 0; u < 4; ++u)
            v[u] = xw2h[(size_t)(((unsigned)e[u].x) >> 10) * 16 + sl];
        #pragma unroll
        for (int u = 0; u < 4; ++u) acc8(esum, v[u], __int_as_float(e[u].y));
    }
    // quad tail
    for (; s + 4 <= s1; s += 4) {
        int sb = __builtin_amdgcn_readfirstlane(s);
        int2 e0 = csr[sb + grp];
        int4 v0 = xw2h[(size_t)(((unsigned)e0.x) >> 10) * 16 + sl];
        acc8(esum, v0, __int_as_float(e0.y));
    }
    // remainder 0..3 edges: clamp index, zero weight for invalid lanes
    if (s < s1) {
        int sb = __builtin_amdgcn_readfirstlane(s);
        int idx = sb + grp;
        int idc = idx < s1 ? idx : s1 - 1;
        int2 e0 = csr[idc];
        int4 v0 = xw2h[(size_t)(((unsigned)e0.x) >> 10) * 16 + sl];
        float n = (idx < s1) ? __int_as_float(e0.y) : 0.0f;
        acc8(esum, v0, n);
    }
    // combine the 4 lane-group partial sums
    #pragma unroll
    for (int k = 0; k < 8; ++k) {
        esum[k] += __shfl_xor(esum[k], 16, 64);
        esum[k] += __shfl_xor(esum[k], 32, 64);
    }
    float dd = d * d;
    float2 f0 = __half22float2(*(__half2*)&sp.x);
    float2 f1 = __half22float2(*(__half2*)&sp.y);
    float2 f2 = __half22float2(*(__half2*)&sp.z);
    float2 f3 = __half22float2(*(__half2*)&sp.w);
    float4 bb0 = ((const float4*)b2)[2 * sl];
    float4 bb1 = ((const float4*)b2)[2 * sl + 1];
    float acc[8];
    acc[0] = bb0.x + f0.x * dd + d * esum[0];
    acc[1] = bb0.y + f0.y * dd + d * esum[1];
    acc[2] = bb0.z + f1.x * dd + d * esum[2];
    acc[3] = bb0.w + f1.y * dd + d * esum[3];
    acc[4] = bb1.x + f2.x * dd + d * esum[4];
    acc[5] = bb1.y + f2.y * dd + d * esum[5];
    acc[6] = bb1.z + f3.x * dd + d * esum[6];
    acc[7] = bb1.w + f3.y * dd + d * esum[7];
    #pragma unroll
    for (int k = 0; k < 8; ++k) acc[k] = acc[k] > 0.f ? acc[k] : 0.f;
    if (grp == 0) {
        #pragma unroll
        for (int k = 0; k < 8; ++k) red[wave][8 * sl + k] = acc[k];
    }
    if (lane == 0) bgs[wave] = batch[c];
    __syncthreads();
    if (wave == 0) {
        float2 a;
        a.x = red[0][2 * lane];
        a.y = red[0][2 * lane + 1];
        int cg = bgs[0];
        #pragma unroll
        for (int w = 1; w < 4; ++w) {
            int g = bgs[w];
            float2 r;
            r.x = red[w][2 * lane];
            r.y = red[w][2 * lane + 1];
            if (g == cg) { a.x += r.x; a.y += r.y; }
            else {
                atomicAdd(&pool[cg * O_DIM + 2 * lane], a.x);
                atomicAdd(&pool[cg * O_DIM + 2 * lane + 1], a.y);
                a = r; cg = g;
            }
        }
        atomicAdd(&pool[cg * O_DIM + 2 * lane], a.x);
        atomicAdd(&pool[cg * O_DIM + 2 * lane + 1], a.y);
    }
}

__global__ void k_final(const float* __restrict__ pool, const float* __restrict__ cnt,
                        float* __restrict__ out) {
    int t = blockIdx.x * blockDim.x + threadIdx.x;
    if (t < N_GRAPH * O_DIM) {
        int g = t / O_DIM;
        out[t] = pool[t] / fmaxf(cnt[g], 1.0f);
    }
}

// ---------------- launch ----------------

extern "C" void kernel_launch(void* const* d_in, const int* in_sizes, int n_in,
                              void* d_out, int out_size, void* d_ws, size_t ws_size,
                              hipStream_t stream) {
    const float* cf   = (const float*)d_in[0];   // [V,128]
    const float* W1   = (const float*)d_in[1];   // [128,256]
    const float* b1   = (const float*)d_in[2];   // [256]
    const float* W2   = (const float*)d_in[3];   // [256,128]
    const float* b2   = (const float*)d_in[4];   // [128]
    const float* ew   = (const float*)d_in[5];   // [E]
    const int*   nidx = (const int*)d_in[6];     // [N]
    const int*   eidx = (const int*)d_in[7];     // [2,E]
    const int*   bidx = (const int*)d_in[8];     // [N]
    float* out = (float*)d_out;

    const int* row = eidx;            // source
    const int* col = eidx + N_EDGES;  // target

    // workspace layout (bytes)
    char* ws = (char*)d_ws;
    size_t off = 0;
    int*   hist  = (int*)  (ws + off); off += (size_t)256 * NBLK * 4;        // 512K
    int*   hoffs = (int*)  (ws + off); off += (size_t)256 * NBLK * 4;        // 512K
    int*   bsum  = (int*)  (ws + off); off += (size_t)NBLK * 4;              // 2K
    unsigned* dcq = (unsigned*)(ws + off); off += (size_t)N_NODES * 4;       // 256K
    float* dis   = (float*)(ws + off); off += (size_t)N_NODES * 4;           // 256K
    int*   offs  = (int*)  (ws + off); off += (size_t)(N_NODES + 16) * 4;    // 256K
    int2*  csr   = (int2*) (ws + off); off += (size_t)N_EDGES * 8;           // 16M
    float* pool  = (float*)(ws + off); off += (size_t)(N_GRAPH * O_DIM + N_GRAPH) * 4;
    __half* cfW1 = (__half*)(ws + off); off += (size_t)V_SIZE * H_DIM * 2;   // 512K
    _Float16* W2T = (_Float16*)(ws + off); off += (size_t)O_DIM * H_DIM * 2; // 64K
    off = (off + 255) & ~(size_t)255;
    int2*  part  = (int2*) (ws + off); off += (size_t)N_EDGES * 8;           // 16M
    __half* h1   = (__half*)(ws + off);                                      // 32M
    __half* xw2h = (__half*)part;    // part dead after k_build2q
    float* cntf  = pool + N_GRAPH * O_DIM;

    // 1. init (pool zero + counts + cfW1 + W2T) + histogram + scans
    k_init<<<256, 256, 0, stream>>>(pool, bidx, cntf, cf, W1, cfW1, W2, W2T);
    k_hist<<<NBLK, 1024, 0, stream>>>(col, hist);
    k_scan1<<<256 * NBLK / 256, 256, 0, stream>>>(hist, hoffs, bsum);
    k_scan2<<<1, 256, 0, stream>>>(bsum);

    // 2. partition -> q-split degree -> dis/offs -> q-split CSR scatter
    k_part<<<NBLK, 1024, 0, stream>>>(row, col, ew, nidx, hoffs, bsum, part);
    k_degq<<<1024, 1024, 0, stream>>>(hoffs, bsum, part, dcq);
    k_disoffs<<<256, 256, 0, stream>>>(dcq, hoffs, bsum, dis, offs);
    k_build2q<<<1024, 1024, 0, stream>>>(hoffs, bsum, part, dis, offs, csr);

    // 3. layer 1: gather-aggregate from the 512 KB cfW1 table -> h1 (fp16)
    k_agg1<<<N_NODES / 4, 256, 0, stream>>>((const int4*)cfW1, nidx, dis, offs, csr,
                                            (const float4*)b1, (int4*)h1);

    // 4. layer 2: MFMA GEMM2, then aggregate + relu + LDS-reduced pool
    k_gemm2<<<N_NODES / 64, 256, 0, stream>>>((const _Float16*)h1, W2T, xw2h);
    k_agg2_pool<<<N_NODES / 4, 256, 0, stream>>>((const int4*)xw2h, b2, dis, offs, csr,
                                                 bidx, pool);

    // 5. final divide
    k_final<<<(N_GRAPH * O_DIM + 255) / 256, 256, 0, stream>>>(pool, cntf, out);
}

// Round 11
// 332.626 us; speedup vs baseline: 1.0013x; 1.0013x over previous
//
#include <hip/hip_runtime.h>
#include <hip/hip_fp16.h>
#include <math.h>

// Problem constants (match reference)
constexpr int N_NODES = 65536;
constexpr int N_EDGES = 2097152;
constexpr int F_IN    = 128;
constexpr int H_DIM   = 256;
constexpr int O_DIM   = 128;
constexpr int N_GRAPH = 256;
constexpr int V_SIZE  = 1000;

// 256 buckets of 256 nodes (bucket = col>>8); 256 edge-blocks of 8192 edges.
constexpr int EPB  = 8192;
constexpr int NBLK = N_EDGES / EPB;   // 256
constexpr float FXP = 16777216.0f;    // 2^24

typedef _Float16 half8 __attribute__((ext_vector_type(8)));
typedef float floatx4 __attribute__((ext_vector_type(4)));

// ---------------- fused init + histogram (512 blocks x 1024) ----------------
// blocks 0..255: init work (pool zero, counts, cfW1, W2T);
// blocks 256..511: per-edge-block bucket histogram. Independent -> overlap.

__global__ void k_init_hist(float* __restrict__ pool, const int* __restrict__ batch,
                            float* __restrict__ cntf, const float* __restrict__ cf,
                            const float* __restrict__ W1, __half* __restrict__ cfW1,
                            const float* __restrict__ W2, _Float16* __restrict__ W2T,
                            const int* __restrict__ col, int* __restrict__ hist) {
    __shared__ float xs[8 * F_IN];    // 4 KB
    __shared__ int h[256];
    int b = blockIdx.x;
    int t = threadIdx.x;
    if (b >= 256) {                   // ---- histogram half ----
        int eb = b - 256;
        if (t < 256) h[t] = 0;
        __syncthreads();
        int base = eb * EPB;
        #pragma unroll
        for (int i = 0; i < EPB / 1024; ++i)
            atomicAdd(&h[col[base + i * 1024 + t] >> 8], 1);
        __syncthreads();
        if (t < 256) hist[t * NBLK + eb] = h[t];   // bucket-major for the scan
        return;
    }
    // ---- init half ----
    int i = b * 1024 + t;
    if (i < N_GRAPH * O_DIM) pool[i] = 0.0f;       // blocks 0..31 cover 32768
    if (b == 0 && t < 256) {
        // batch_index sorted: per-graph counts via binary search, no atomics
        int g = t;
        int lo = 0, hi = N_NODES;
        while (lo < hi) { int m = (lo + hi) >> 1; if (batch[m] < g) lo = m + 1; else hi = m; }
        int start = lo;
        lo = 0; hi = N_NODES;
        while (lo < hi) { int m = (lo + hi) >> 1; if (batch[m] <= g) lo = m + 1; else hi = m; }
        cntf[g] = (float)(lo - start);
    }
    if (b < V_SIZE / 8) {             // 125 blocks compute the cfW1 table
        int rb = b * 8;
        // 1024 threads: col ct = t&255, row-pair group g2 = t>>8 (rows g2*2, g2*2+1)
        xs[t] = cf[(size_t)(rb + (t >> 7)) * F_IN + (t & 127)];
        __syncthreads();
        int ct = t & 255, g2 = t >> 8;
        float a0 = 0.f, a1 = 0.f;
        const float* x0 = &xs[(g2 * 2) * F_IN];
        const float* x1 = &xs[(g2 * 2 + 1) * F_IN];
        for (int k = 0; k < F_IN; ++k) {
            float w = W1[k * H_DIM + ct];
            a0 += x0[k] * w;
            a1 += x1[k] * w;
        }
        cfW1[(size_t)(rb + g2 * 2) * H_DIM + ct]     = __float2half(a0);
        cfW1[(size_t)(rb + g2 * 2 + 1) * H_DIM + ct] = __float2half(a1);
    }
    if (b >= 128 && b < 160) {        // 32 blocks: W2T transpose fp32->fp16
        int idx = (b - 128) * 1024 + t;               // 0..32767
        int nn = idx >> 8, kk = idx & 255;
        W2T[idx] = (_Float16)W2[kk * O_DIM + nn];
    }
}

// ---------------- scan (partial per-256-chunk + raw chunk sums) -------------
// chunk cb == bucket cb (NBLK==256): hoffs = within-bucket prefix, bsum raw.

__global__ void k_scan1(const int* __restrict__ in, int* __restrict__ out,
                        int* __restrict__ bsum) {
    __shared__ int s[256];
    int tid = threadIdx.x;
    int i = blockIdx.x * 256 + tid;
    int v = in[i];
    s[tid] = v;
    __syncthreads();
    for (int d = 1; d < 256; d <<= 1) {
        int t = (tid >= d) ? s[tid - d] : 0;
        __syncthreads();
        s[tid] += t;
        __syncthreads();
    }
    out[i] = s[tid] - v;
    if (tid == 255) bsum[blockIdx.x] = s[255];
}

// inline 256-wide exclusive scan of raw bsum -> exc[0..256] (all threads barrier)
__device__ __forceinline__ void scan_bsum(const int* __restrict__ bsum,
                                          int* __restrict__ sbuf,
                                          int* __restrict__ exc, int t) {
    if (t < 256) sbuf[t] = bsum[t];
    __syncthreads();
    for (int d = 1; d < 256; d <<= 1) {
        int x = (t < 256 && t >= d) ? sbuf[t - d] : 0;
        __syncthreads();
        if (t < 256) sbuf[t] += x;
        __syncthreads();
    }
    if (t < 256) exc[t + 1] = sbuf[t];
    if (t == 0) exc[0] = 0;
    __syncthreads();
}

// ---------------- stage C: partition into int2 records (256 blocks x 1024) --
// rec.x = src:16 | dst8:8 | vocab_hi:8 ; rec.y = vocab_lo:2<<16 | ew_fp16:16

__global__ void k_part(const int* __restrict__ row, const int* __restrict__ col,
                       const float* __restrict__ ew, const int* __restrict__ nidx,
                       const int* __restrict__ hoffs, const int* __restrict__ bsum,
                       int2* __restrict__ part) {
    __shared__ int cur[256];
    __shared__ int sbuf[256];
    __shared__ int exc[257];
    int t = threadIdx.x;
    scan_bsum(bsum, sbuf, exc, t);
    if (t < 256) cur[t] = hoffs[t * NBLK + blockIdx.x] + exc[t];
    __syncthreads();
    int base = blockIdx.x * EPB;
    #pragma unroll
    for (int i = 0; i < EPB / 1024; ++i) {
        int e = base + i * 1024 + t;
        int r = row[e], c = col[e];
        unsigned hw = (unsigned)__half_as_ushort(__float2half(ew[e]));
        int vb = nidx[r];
        int slot = atomicAdd(&cur[c >> 8], 1);
        int2 rec;
        rec.x = (r << 16) | ((c & 255) << 8) | (vb >> 2);
        rec.y = (int)(((unsigned)(vb & 3) << 16) | hw);
        part[slot] = rec;
    }
}

// ---------------- stage D1: per-bucket deg/dis + offs (256 blocks x 1024) ---

__global__ void k_build1(const int* __restrict__ hoffs, const int* __restrict__ bsum,
                         const int2* __restrict__ part, float* __restrict__ dis,
                         int* __restrict__ offs) {
    __shared__ unsigned long long dc[256];
    __shared__ int sc[256];
    __shared__ int sbuf[256];
    __shared__ int exc[257];
    int t = threadIdx.x;
    int bucket = blockIdx.x;
    scan_bsum(bsum, sbuf, exc, t);
    if (t < 256) dc[t] = 0ULL;
    __syncthreads();
    int start = hoffs[bucket * NBLK] + exc[bucket];
    int end   = (bucket == 255) ? N_EDGES : (hoffs[(bucket + 1) * NBLK] + exc[bucket + 1]);
    for (int j = start + t; j < end; j += 1024) {
        int2 rec = part[j];
        int dst = (rec.x >> 8) & 255;
        float w = __half2float(__ushort_as_half((unsigned short)(rec.y & 0xFFFF)));
        atomicAdd(&dc[dst], (1ULL << 40) |
                  (unsigned long long)(unsigned)(w * FXP + 0.5f));
    }
    __syncthreads();
    unsigned long long v = (t < 256) ? dc[t] : 0ULL;
    if (t < 256) {
        float deg = 1.0f + (float)(v & 0xFFFFFFFFFFULL) * (1.0f / FXP);   // self-loop +1
        dis[bucket * 256 + t] = 1.0f / sqrtf(deg);                        // deg >= 1
        sc[t] = (int)(v >> 40);
    }
    __syncthreads();
    for (int d = 1; d < 256; d <<= 1) {
        int x = (t >= d && t < 256) ? sc[t - d] : 0;
        __syncthreads();
        if (t < 256) sc[t] += x;
        __syncthreads();
    }
    if (t < 256) {
        int cnt = (int)(v >> 40);
        offs[bucket * 256 + t] = start + sc[t] - cnt;
    }
    if (bucket == 255 && t == 255) offs[N_NODES] = N_EDGES;
}

// ---------------- stage D2: scatter to final CSR (256 blocks x 1024) --------
// csr.x = src<<10 | vocab ; csr.y = dis[src] * ew (dis[dst] applied in agg).

__global__ void k_build2(const int* __restrict__ hoffs, const int* __restrict__ bsum,
                         const int2* __restrict__ part, const float* __restrict__ dis,
                         const int* __restrict__ offs, int2* __restrict__ csr) {
    __shared__ int cur[256];
    __shared__ int sbuf[256];
    __shared__ int exc[257];
    int t = threadIdx.x;
    int bucket = blockIdx.x;
    scan_bsum(bsum, sbuf, exc, t);
    if (t < 256) cur[t] = offs[bucket * 256 + t];
    __syncthreads();
    int start = hoffs[bucket * NBLK] + exc[bucket];
    int end   = (bucket == 255) ? N_EDGES : (hoffs[(bucket + 1) * NBLK] + exc[bucket + 1]);
    for (int j = start + t; j < end; j += 1024) {
        int2 rec = part[j];
        int dst = (rec.x >> 8) & 255;
        unsigned src = ((unsigned)rec.x) >> 16;
        int vb = ((rec.x & 255) << 2) | ((rec.y >> 16) & 3);
        float w = __half2float(__ushort_as_half((unsigned short)(rec.y & 0xFFFF)));
        float nm = dis[src] * w;
        int slot = atomicAdd(&cur[dst], 1);
        int2 e;
        e.x = (int)((src << 10) | (unsigned)vb);
        e.y = __float_as_int(nm);
        csr[slot] = e;
    }
}

// 8-half fp16 row-fragment accumulate: e[k] += f32(v[k]) * n
__device__ __forceinline__ void acc8(float* e, int4 v, float n) {
    float2 f0 = __half22float2(*(__half2*)&v.x);
    float2 f1 = __half22float2(*(__half2*)&v.y);
    float2 f2 = __half22float2(*(__half2*)&v.z);
    float2 f3 = __half22float2(*(__half2*)&v.w);
    e[0] += f0.x * n; e[1] += f0.y * n;
    e[2] += f1.x * n; e[3] += f1.y * n;
    e[4] += f2.x * n; e[5] += f2.y * n;
    e[6] += f3.x * n; e[7] += f3.y * n;
}

// ---------------- layer-1: gather-aggregate cfW1 rows -> h1 -----------------
// Wave per node; 2 edges per gather instr; DEEPENED: 8 gathers (16 edges) in
// flight per batch against the ~200cy L2 latency. launch_bounds(256,4) caps
// VGPR at 128 (4 waves/EU = 16 waves/CU).

__global__ void __launch_bounds__(256, 4) k_agg1(
        const int4* __restrict__ cfW1, const int* __restrict__ nidx,
        const float* __restrict__ dis, const int* __restrict__ offs,
        const int2* __restrict__ csr, const float4* __restrict__ b1f4,
        int4* __restrict__ h1) {
    int wave = threadIdx.x >> 6;
    int lane = threadIdx.x & 63;
    int g    = lane >> 5;        // which edge of the pair
    int sl   = lane & 31;        // int4 slot within the 256-half row
    int c = blockIdx.x * 4 + wave;
    float d = dis[c];
    int4 sp = cfW1[(size_t)nidx[c] * 32 + sl];
    float esum[8] = {0.f, 0.f, 0.f, 0.f, 0.f, 0.f, 0.f, 0.f};
    int a0 = offs[c], a1 = offs[c + 1];
    int s = a0;
    // peel one edge if start is odd (keeps scalar int4 loads 16B-aligned)
    if (s < a1 && (s & 1)) {
        int sb = __builtin_amdgcn_readfirstlane(s);
        int2 e0 = csr[sb];
        int4 v0 = cfW1[(size_t)(e0.x & 1023) * 32 + sl];
        float n = (g == 0) ? __int_as_float(e0.y) : 0.0f;
        acc8(esum, v0, n);
        ++s;
    }
    // main: 8 pairs (16 edges) per batch, 8 int4 gathers in flight
    for (; s + 16 <= a1; s += 16) {
        int sb = __builtin_amdgcn_readfirstlane(s);
        int4 ee[8];
        #pragma unroll
        for (int u = 0; u < 8; ++u) ee[u] = *(const int4*)(csr + sb + 2 * u);
        int4 v[8]; float n[8];
        #pragma unroll
        for (int u = 0; u < 8; ++u) {
            int ex = g ? ee[u].z : ee[u].x;
            int ey = g ? ee[u].w : ee[u].y;
            n[u] = __int_as_float(ey);
            v[u] = cfW1[(size_t)(ex & 1023) * 32 + sl];
        }
        #pragma unroll
        for (int u = 0; u < 8; ++u) acc8(esum, v[u], n[u]);
    }
    // 8-edge batch
    if (s + 8 <= a1) {
        int sb = __builtin_amdgcn_readfirstlane(s);
        int4 ee[4];
        #pragma unroll
        for (int u = 0; u < 4; ++u) ee[u] = *(const int4*)(csr + sb + 2 * u);
        int4 v[4]; float n[4];
        #pragma unroll
        for (int u = 0; u < 4; ++u) {
            int ex = g ? ee[u].z : ee[u].x;
            int ey = g ? ee[u].w : ee[u].y;
            n[u] = __int_as_float(ey);
            v[u] = cfW1[(size_t)(ex & 1023) * 32 + sl];
        }
        #pragma unroll
        for (int u = 0; u < 4; ++u) acc8(esum, v[u], n[u]);
        s += 8;
    }
    // pair tail
    for (; s + 2 <= a1; s += 2) {
        int sb = __builtin_amdgcn_readfirstlane(s);
        int4 ee = *(const int4*)(csr + sb);
        int ex = g ? ee.z : ee.x;
        int ey = g ? ee.w : ee.y;
        int4 v0 = cfW1[(size_t)(ex & 1023) * 32 + sl];
        acc8(esum, v0, __int_as_float(ey));
    }
    // single tail
    if (s < a1) {
        int sb = __builtin_amdgcn_readfirstlane(s);
        int2 e0 = csr[sb];
        int4 v0 = cfW1[(size_t)(e0.x & 1023) * 32 + sl];
        float n = (g == 0) ? __int_as_float(e0.y) : 0.0f;
        acc8(esum, v0, n);
    }
    // combine the two half-wave partial sums
    #pragma unroll
    for (int k = 0; k < 8; ++k) esum[k] += __shfl_xor(esum[k], 32, 64);

    float dd = d * d;
    float2 s0 = __half22float2(*(__half2*)&sp.x);
    float2 s1 = __half22float2(*(__half2*)&sp.y);
    float2 s2 = __half22float2(*(__half2*)&sp.z);
    float2 s3 = __half22float2(*(__half2*)&sp.w);
    float4 bb0 = b1f4[2 * sl];
    float4 bb1 = b1f4[2 * sl + 1];
    float r[8];
    r[0] = bb0.x + s0.x * dd + d * esum[0];
    r[1] = bb0.y + s0.y * dd + d * esum[1];
    r[2] = bb0.z + s1.x * dd + d * esum[2];
    r[3] = bb0.w + s1.y * dd + d * esum[3];
    r[4] = bb1.x + s2.x * dd + d * esum[4];
    r[5] = bb1.y + s2.y * dd + d * esum[5];
    r[6] = bb1.z + s3.x * dd + d * esum[6];
    r[7] = bb1.w + s3.y * dd + d * esum[7];
    #pragma unroll
    for (int k = 0; k < 8; ++k) r[k] = r[k] > 0.f ? r[k] : 0.f;
    float2 p0 = {r[0], r[1]}, p1 = {r[2], r[3]}, p2 = {r[4], r[5]}, p3 = {r[6], r[7]};
    __half2 h0 = __float22half2_rn(p0);
    __half2 h1v = __float22half2_rn(p1);
    __half2 h2 = __float22half2_rn(p2);
    __half2 h3 = __float22half2_rn(p3);
    int4 outv;
    outv.x = *(int*)&h0;
    outv.y = *(int*)&h1v;
    outv.z = *(int*)&h2;
    outv.w = *(int*)&h3;
    if (lane < 32) h1[(size_t)c * 32 + sl] = outv;
}

// ---------------- GEMM2 via MFMA: h1 [N,256] fp16 @ W2 -> xw2h fp16 ---------

__global__ void k_gemm2(const _Float16* __restrict__ h1, const _Float16* __restrict__ W2T,
                        __half* __restrict__ xw2h) {
    int wave = threadIdx.x >> 6;
    int lane = threadIdx.x & 63;
    int quad = lane >> 4;
    int n    = lane & 15;
    int tm   = blockIdx.x * 4 + wave;                  // 16-row tile index
    const _Float16* arow = h1 + (size_t)(tm * 16 + n) * H_DIM;
    half8 a[8];
    #pragma unroll
    for (int kt = 0; kt < 8; ++kt)
        a[kt] = *(const half8*)(arow + kt * 32 + quad * 8);
    #pragma unroll
    for (int nt = 0; nt < 8; ++nt) {
        floatx4 acc = {0.f, 0.f, 0.f, 0.f};
        const _Float16* brow = W2T + (size_t)(nt * 16 + n) * H_DIM;
        #pragma unroll
        for (int kt = 0; kt < 8; ++kt) {
            half8 b = *(const half8*)(brow + kt * 32 + quad * 8);
            acc = __builtin_amdgcn_mfma_f32_16x16x32_f16(a[kt], b, acc, 0, 0, 0);
        }
        #pragma unroll
        for (int r = 0; r < 4; ++r) {
            int rowi = tm * 16 + quad * 4 + r;
            xw2h[(size_t)rowi * O_DIM + nt * 16 + n] = __float2half(acc[r]);
        }
    }
}

// ---------------- layer-2 agg + relu + LDS-reduced pool (R1-exact) ----------

__global__ void k_agg2_pool(const int4* __restrict__ xw2h, const float* __restrict__ b2,
                            const float* __restrict__ dis, const int* __restrict__ offs,
                            const int2* __restrict__ csr, const int* __restrict__ batch,
                            float* __restrict__ pool) {
    __shared__ float red[4][128];
    __shared__ int bgs[4];
    int wave = threadIdx.x >> 6;
    int lane = threadIdx.x & 63;
    int grp  = lane >> 4;        // which edge of the quad
    int sl   = lane & 15;        // int4 slot within the 128-half row
    int c = blockIdx.x * 4 + wave;
    float d = dis[c];
    int4 sp = xw2h[(size_t)c * 16 + sl];
    float esum[8] = {0.f, 0.f, 0.f, 0.f, 0.f, 0.f, 0.f, 0.f};
    int s0 = offs[c], s1 = offs[c + 1];
    int s = s0;
    // main: 4 quads (16 edges) per batch, 4 int4 gathers in flight
    for (; s + 16 <= s1; s += 16) {
        int sb = __builtin_amdgcn_readfirstlane(s);
        int2 e[4];
        #pragma unroll
        for (int u = 0; u < 4; ++u) e[u] = csr[sb + 4 * u + grp];
        int4 v[4];
        #pragma unroll
        for (int u = 0; u < 4; ++u)
            v[u] = xw2h[(size_t)(((unsigned)e[u].x) >> 10) * 16 + sl];
        #pragma unroll
        for (int u = 0; u < 4; ++u) acc8(esum, v[u], __int_as_float(e[u].y));
    }
    // quad tail
    for (; s + 4 <= s1; s += 4) {
        int sb = __builtin_amdgcn_readfirstlane(s);
        int2 e0 = csr[sb + grp];
        int4 v0 = xw2h[(size_t)(((unsigned)e0.x) >> 10) * 16 + sl];
        acc8(esum, v0, __int_as_float(e0.y));
    }
    // remainder 0..3 edges: clamp index, zero weight for invalid lanes
    if (s < s1) {
        int sb = __builtin_amdgcn_readfirstlane(s);
        int idx = sb + grp;
        int idc = idx < s1 ? idx : s1 - 1;
        int2 e0 = csr[idc];
        int4 v0 = xw2h[(size_t)(((unsigned)e0.x) >> 10) * 16 + sl];
        float n = (idx < s1) ? __int_as_float(e0.y) : 0.0f;
        acc8(esum, v0, n);
    }
    // combine the 4 lane-group partial sums
    #pragma unroll
    for (int k = 0; k < 8; ++k) {
        esum[k] += __shfl_xor(esum[k], 16, 64);
        esum[k] += __shfl_xor(esum[k], 32, 64);
    }
    float dd = d * d;
    float2 f0 = __half22float2(*(__half2*)&sp.x);
    float2 f1 = __half22float2(*(__half2*)&sp.y);
    float2 f2 = __half22float2(*(__half2*)&sp.z);
    float2 f3 = __half22float2(*(__half2*)&sp.w);
    float4 bb0 = ((const float4*)b2)[2 * sl];
    float4 bb1 = ((const float4*)b2)[2 * sl + 1];
    float acc[8];
    acc[0] = bb0.x + f0.x * dd + d * esum[0];
    acc[1] = bb0.y + f0.y * dd + d * esum[1];
    acc[2] = bb0.z + f1.x * dd + d * esum[2];
    acc[3] = bb0.w + f1.y * dd + d * esum[3];
    acc[4] = bb1.x + f2.x * dd + d * esum[4];
    acc[5] = bb1.y + f2.y * dd + d * esum[5];
    acc[6] = bb1.z + f3.x * dd + d * esum[6];
    acc[7] = bb1.w + f3.y * dd + d * esum[7];
    #pragma unroll
    for (int k = 0; k < 8; ++k) acc[k] = acc[k] > 0.f ? acc[k] : 0.f;
    if (grp == 0) {
        #pragma unroll
        for (int k = 0; k < 8; ++k) red[wave][8 * sl + k] = acc[k];
    }
    if (lane == 0) bgs[wave] = batch[c];
    __syncthreads();
    if (wave == 0) {
        float2 a;
        a.x = red[0][2 * lane];
        a.y = red[0][2 * lane + 1];
        int cg = bgs[0];
        #pragma unroll
        for (int w = 1; w < 4; ++w) {
            int g = bgs[w];
            float2 r;
            r.x = red[w][2 * lane];
            r.y = red[w][2 * lane + 1];
            if (g == cg) { a.x += r.x; a.y += r.y; }
            else {
                atomicAdd(&pool[cg * O_DIM + 2 * lane], a.x);
                atomicAdd(&pool[cg * O_DIM + 2 * lane + 1], a.y);
                a = r; cg = g;
            }
        }
        atomicAdd(&pool[cg * O_DIM + 2 * lane], a.x);
        atomicAdd(&pool[cg * O_DIM + 2 * lane + 1], a.y);
    }
}

__global__ void k_final(const float* __restrict__ pool, const float* __restrict__ cnt,
                        float* __restrict__ out) {
    int t = blockIdx.x * blockDim.x + threadIdx.x;
    if (t < N_GRAPH * O_DIM) {
        int g = t / O_DIM;
        out[t] = pool[t] / fmaxf(cnt[g], 1.0f);
    }
}

// ---------------- launch ----------------

extern "C" void kernel_launch(void* const* d_in, const int* in_sizes, int n_in,
                              void* d_out, int out_size, void* d_ws, size_t ws_size,
                              hipStream_t stream) {
    const float* cf   = (const float*)d_in[0];   // [V,128]
    const float* W1   = (const float*)d_in[1];   // [128,256]
    const float* b1   = (const float*)d_in[2];   // [256]
    const float* W2   = (const float*)d_in[3];   // [256,128]
    const float* b2   = (const float*)d_in[4];   // [128]
    const float* ew   = (const float*)d_in[5];   // [E]
    const int*   nidx = (const int*)d_in[6];     // [N]
    const int*   eidx = (const int*)d_in[7];     // [2,E]
    const int*   bidx = (const int*)d_in[8];     // [N]
    float* out = (float*)d_out;

    const int* row = eidx;            // source
    const int* col = eidx + N_EDGES;  // target

    // workspace layout (bytes)
    char* ws = (char*)d_ws;
    size_t off = 0;
    int*   hist  = (int*)  (ws + off); off += (size_t)N_NODES * 4;          // 256K
    int*   hoffs = (int*)  (ws + off); off += (size_t)N_NODES * 4;          // 256K
    int*   bsum  = (int*)  (ws + off); off += 4096;
    float* dis   = (float*)(ws + off); off += (size_t)N_NODES * 4;          // 256K
    int*   offs  = (int*)  (ws + off); off += (size_t)(N_NODES + 16) * 4;   // 256K
    int2*  csr   = (int2*) (ws + off); off += (size_t)N_EDGES * 8;          // 16M
    float* pool  = (float*)(ws + off); off += (size_t)(N_GRAPH * O_DIM + N_GRAPH) * 4;
    __half* cfW1 = (__half*)(ws + off); off += (size_t)V_SIZE * H_DIM * 2;  // 512K
    _Float16* W2T = (_Float16*)(ws + off); off += (size_t)O_DIM * H_DIM * 2; // 64K
    off = (off + 255) & ~(size_t)255;
    int2*  part  = (int2*) (ws + off); off += (size_t)N_EDGES * 8;          // 16M
    __half* h1   = (__half*)(ws + off);                                     // 32M
    __half* xw2h = (__half*)part;    // part dead after k_build2
    float* cntf  = pool + N_GRAPH * O_DIM;

    // 1. fused init + histogram, then partial scan (bsum stays raw)
    k_init_hist<<<512, 1024, 0, stream>>>(pool, bidx, cntf, cf, W1, cfW1, W2, W2T,
                                          col, hist);
    k_scan1<<<256, 256, 0, stream>>>(hist, hoffs, bsum);

    // 2. partition -> build1 (deg/dis/offs) -> build2 (CSR w/ nrm applied)
    //    (each does the cheap 256-wide bsum scan in its prologue)
    k_part<<<NBLK, 1024, 0, stream>>>(row, col, ew, nidx, hoffs, bsum, part);
    k_build1<<<256, 1024, 0, stream>>>(hoffs, bsum, part, dis, offs);
    k_build2<<<256, 1024, 0, stream>>>(hoffs, bsum, part, dis, offs, csr);

    // 3. layer 1: gather-aggregate from the 512 KB cfW1 table -> h1 (fp16)
    k_agg1<<<N_NODES / 4, 256, 0, stream>>>((const int4*)cfW1, nidx, dis, offs, csr,
                                            (const float4*)b1, (int4*)h1);

    // 4. layer 2: MFMA GEMM2, then aggregate + relu + LDS-reduced pool
    k_gemm2<<<N_NODES / 64, 256, 0, stream>>>((const _Float16*)h1, W2T, xw2h);
    k_agg2_pool<<<N_NODES / 4, 256, 0, stream>>>((const int4*)xw2h, b2, dis, offs, csr,
                                                 bidx, pool);

    // 5. final divide
    k_final<<<(N_GRAPH * O_DIM + 255) / 256, 256, 0, stream>>>(pool, cntf, out);
}

// Round 12
// 325.504 us; speedup vs baseline: 1.0232x; 1.0219x over previous
//
#include <hip/hip_runtime.h>
#include <hip/hip_fp16.h>
#include <math.h>

// Problem constants (match reference)
constexpr int N_NODES = 65536;
constexpr int N_EDGES = 2097152;
constexpr int F_IN    = 128;
constexpr int H_DIM   = 256;
constexpr int O_DIM   = 128;
constexpr int N_GRAPH = 256;
constexpr int V_SIZE  = 1000;

// 256 buckets of 256 nodes (bucket = col>>8); 256 edge-blocks of 8192 edges.
constexpr int EPB  = 8192;
constexpr int NBLK = N_EDGES / EPB;   // 256
constexpr float FXP = 16777216.0f;    // 2^24

typedef _Float16 half8 __attribute__((ext_vector_type(8)));
typedef float floatx4 __attribute__((ext_vector_type(4)));

// ---------------- fused init + histogram (512 blocks x 1024) ----------------
// blocks 0..255: init work (pool zero, counts, cfW1, W2T);
// blocks 256..511: per-edge-block bucket histogram. Independent -> overlap.

__global__ void k_init_hist(float* __restrict__ pool, const int* __restrict__ batch,
                            float* __restrict__ cntf, const float* __restrict__ cf,
                            const float* __restrict__ W1, __half* __restrict__ cfW1,
                            const float* __restrict__ W2, _Float16* __restrict__ W2T,
                            const int* __restrict__ col, int* __restrict__ hist) {
    __shared__ float xs[8 * F_IN];    // 4 KB
    __shared__ int h[256];
    int b = blockIdx.x;
    int t = threadIdx.x;
    if (b >= 256) {                   // ---- histogram half ----
        int eb = b - 256;
        if (t < 256) h[t] = 0;
        __syncthreads();
        int base = eb * EPB;
        #pragma unroll
        for (int i = 0; i < EPB / 1024; ++i)
            atomicAdd(&h[col[base + i * 1024 + t] >> 8], 1);
        __syncthreads();
        if (t < 256) hist[t * NBLK + eb] = h[t];   // bucket-major for the scan
        return;
    }
    // ---- init half ----
    int i = b * 1024 + t;
    if (i < N_GRAPH * O_DIM) pool[i] = 0.0f;       // blocks 0..31 cover 32768
    if (b == 0 && t < 256) {
        // batch_index sorted: per-graph counts via binary search, no atomics
        int g = t;
        int lo = 0, hi = N_NODES;
        while (lo < hi) { int m = (lo + hi) >> 1; if (batch[m] < g) lo = m + 1; else hi = m; }
        int start = lo;
        lo = 0; hi = N_NODES;
        while (lo < hi) { int m = (lo + hi) >> 1; if (batch[m] <= g) lo = m + 1; else hi = m; }
        cntf[g] = (float)(lo - start);
    }
    if (b < V_SIZE / 8) {             // 125 blocks compute the cfW1 table
        int rb = b * 8;
        // 1024 threads: col ct = t&255, row-pair group g2 = t>>8 (rows g2*2, g2*2+1)
        xs[t] = cf[(size_t)(rb + (t >> 7)) * F_IN + (t & 127)];
        __syncthreads();
        int ct = t & 255, g2 = t >> 8;
        float a0 = 0.f, a1 = 0.f;
        const float* x0 = &xs[(g2 * 2) * F_IN];
        const float* x1 = &xs[(g2 * 2 + 1) * F_IN];
        for (int k = 0; k < F_IN; ++k) {
            float w = W1[k * H_DIM + ct];
            a0 += x0[k] * w;
            a1 += x1[k] * w;
        }
        cfW1[(size_t)(rb + g2 * 2) * H_DIM + ct]     = __float2half(a0);
        cfW1[(size_t)(rb + g2 * 2 + 1) * H_DIM + ct] = __float2half(a1);
    }
    if (b >= 128 && b < 160) {        // 32 blocks: W2T transpose fp32->fp16
        int idx = (b - 128) * 1024 + t;               // 0..32767
        int nn = idx >> 8, kk = idx & 255;
        W2T[idx] = (_Float16)W2[kk * O_DIM + nn];
    }
}

// ---------------- scan (partial per-256-chunk + raw chunk sums) -------------
// chunk cb == bucket cb (NBLK==256): hoffs = within-bucket prefix, bsum raw.

__global__ void k_scan1(const int* __restrict__ in, int* __restrict__ out,
                        int* __restrict__ bsum) {
    __shared__ int s[256];
    int tid = threadIdx.x;
    int i = blockIdx.x * 256 + tid;
    int v = in[i];
    s[tid] = v;
    __syncthreads();
    for (int d = 1; d < 256; d <<= 1) {
        int t = (tid >= d) ? s[tid - d] : 0;
        __syncthreads();
        s[tid] += t;
        __syncthreads();
    }
    out[i] = s[tid] - v;
    if (tid == 255) bsum[blockIdx.x] = s[255];
}

// inline 256-wide exclusive scan of raw bsum -> exc[0..256] (all threads barrier)
__device__ __forceinline__ void scan_bsum(const int* __restrict__ bsum,
                                          int* __restrict__ sbuf,
                                          int* __restrict__ exc, int t) {
    if (t < 256) sbuf[t] = bsum[t];
    __syncthreads();
    for (int d = 1; d < 256; d <<= 1) {
        int x = (t < 256 && t >= d) ? sbuf[t - d] : 0;
        __syncthreads();
        if (t < 256) sbuf[t] += x;
        __syncthreads();
    }
    if (t < 256) exc[t + 1] = sbuf[t];
    if (t == 0) exc[0] = 0;
    __syncthreads();
}

// ---------------- stage C: partition into int2 records (256 blocks x 1024) --
// rec.x = src:16 | dst8:8 | vocab_hi:8 ; rec.y = vocab_lo:2<<16 | ew_fp16:16

__global__ void k_part(const int* __restrict__ row, const int* __restrict__ col,
                       const float* __restrict__ ew, const int* __restrict__ nidx,
                       const int* __restrict__ hoffs, const int* __restrict__ bsum,
                       int2* __restrict__ part) {
    __shared__ int cur[256];
    __shared__ int sbuf[256];
    __shared__ int exc[257];
    int t = threadIdx.x;
    scan_bsum(bsum, sbuf, exc, t);
    if (t < 256) cur[t] = hoffs[t * NBLK + blockIdx.x] + exc[t];
    __syncthreads();
    int base = blockIdx.x * EPB;
    #pragma unroll
    for (int i = 0; i < EPB / 1024; ++i) {
        int e = base + i * 1024 + t;
        int r = row[e], c = col[e];
        unsigned hw = (unsigned)__half_as_ushort(__float2half(ew[e]));
        int vb = nidx[r];
        int slot = atomicAdd(&cur[c >> 8], 1);
        int2 rec;
        rec.x = (r << 16) | ((c & 255) << 8) | (vb >> 2);
        rec.y = (int)(((unsigned)(vb & 3) << 16) | hw);
        part[slot] = rec;
    }
}

// ---------------- stage D1: per-bucket deg/dis + offs (256 blocks x 1024) ---

__global__ void k_build1(const int* __restrict__ hoffs, const int* __restrict__ bsum,
                         const int2* __restrict__ part, float* __restrict__ dis,
                         int* __restrict__ offs) {
    __shared__ unsigned long long dc[256];
    __shared__ int sc[256];
    __shared__ int sbuf[256];
    __shared__ int exc[257];
    int t = threadIdx.x;
    int bucket = blockIdx.x;
    scan_bsum(bsum, sbuf, exc, t);
    if (t < 256) dc[t] = 0ULL;
    __syncthreads();
    int start = hoffs[bucket * NBLK] + exc[bucket];
    int end   = (bucket == 255) ? N_EDGES : (hoffs[(bucket + 1) * NBLK] + exc[bucket + 1]);
    for (int j = start + t; j < end; j += 1024) {
        int2 rec = part[j];
        int dst = (rec.x >> 8) & 255;
        float w = __half2float(__ushort_as_half((unsigned short)(rec.y & 0xFFFF)));
        atomicAdd(&dc[dst], (1ULL << 40) |
                  (unsigned long long)(unsigned)(w * FXP + 0.5f));
    }
    __syncthreads();
    unsigned long long v = (t < 256) ? dc[t] : 0ULL;
    if (t < 256) {
        float deg = 1.0f + (float)(v & 0xFFFFFFFFFFULL) * (1.0f / FXP);   // self-loop +1
        dis[bucket * 256 + t] = 1.0f / sqrtf(deg);                        // deg >= 1
        sc[t] = (int)(v >> 40);
    }
    __syncthreads();
    for (int d = 1; d < 256; d <<= 1) {
        int x = (t >= d && t < 256) ? sc[t - d] : 0;
        __syncthreads();
        if (t < 256) sc[t] += x;
        __syncthreads();
    }
    if (t < 256) {
        int cnt = (int)(v >> 40);
        offs[bucket * 256 + t] = start + sc[t] - cnt;
    }
    if (bucket == 255 && t == 255) offs[N_NODES] = N_EDGES;
}

// ---------------- stage D2: scatter to final CSR (256 blocks x 1024) --------
// csr.x = src<<10 | vocab ; csr.y = dis[src] * ew (dis[dst] applied in agg).

__global__ void k_build2(const int* __restrict__ hoffs, const int* __restrict__ bsum,
                         const int2* __restrict__ part, const float* __restrict__ dis,
                         const int* __restrict__ offs, int2* __restrict__ csr) {
    __shared__ int cur[256];
    __shared__ int sbuf[256];
    __shared__ int exc[257];
    int t = threadIdx.x;
    int bucket = blockIdx.x;
    scan_bsum(bsum, sbuf, exc, t);
    if (t < 256) cur[t] = offs[bucket * 256 + t];
    __syncthreads();
    int start = hoffs[bucket * NBLK] + exc[bucket];
    int end   = (bucket == 255) ? N_EDGES : (hoffs[(bucket + 1) * NBLK] + exc[bucket + 1]);
    for (int j = start + t; j < end; j += 1024) {
        int2 rec = part[j];
        int dst = (rec.x >> 8) & 255;
        unsigned src = ((unsigned)rec.x) >> 16;
        int vb = ((rec.x & 255) << 2) | ((rec.y >> 16) & 3);
        float w = __half2float(__ushort_as_half((unsigned short)(rec.y & 0xFFFF)));
        float nm = dis[src] * w;
        int slot = atomicAdd(&cur[dst], 1);
        int2 e;
        e.x = (int)((src << 10) | (unsigned)vb);
        e.y = __float_as_int(nm);
        csr[slot] = e;
    }
}

// 8-half fp16 row-fragment accumulate: e[k] += f32(v[k]) * n
__device__ __forceinline__ void acc8(float* e, int4 v, float n) {
    float2 f0 = __half22float2(*(__half2*)&v.x);
    float2 f1 = __half22float2(*(__half2*)&v.y);
    float2 f2 = __half22float2(*(__half2*)&v.z);
    float2 f3 = __half22float2(*(__half2*)&v.w);
    e[0] += f0.x * n; e[1] += f0.y * n;
    e[2] += f1.x * n; e[3] += f1.y * n;
    e[4] += f2.x * n; e[5] += f2.y * n;
    e[6] += f3.x * n; e[7] += f3.y * n;
}

// ---------------- layer-1: gather-aggregate cfW1 rows -> h1 -----------------
// R9 structure (4 gathers / 8 edges, VGPR-light) + SCALAR-PIPELINED csr reads:
// the uniform csr batch for iteration i+1 is s_loaded (SGPRs, free) while
// iteration i's vector gathers are in flight -> breaks the s_load->gather
// serial latency chain at zero occupancy cost.

__global__ void k_agg1(const int4* __restrict__ cfW1, const int* __restrict__ nidx,
                       const float* __restrict__ dis, const int* __restrict__ offs,
                       const int2* __restrict__ csr, const float4* __restrict__ b1f4,
                       int4* __restrict__ h1) {
    int wave = threadIdx.x >> 6;
    int lane = threadIdx.x & 63;
    int g    = lane >> 5;        // which edge of the pair
    int sl   = lane & 31;        // int4 slot within the 256-half row
    int c = blockIdx.x * 4 + wave;
    float d = dis[c];
    int4 sp = cfW1[(size_t)nidx[c] * 32 + sl];
    float esum[8] = {0.f, 0.f, 0.f, 0.f, 0.f, 0.f, 0.f, 0.f};
    int a0 = offs[c], a1 = offs[c + 1];
    int s = a0;
    // peel one edge if start is odd (keeps scalar int4 loads 16B-aligned)
    if (s < a1 && (s & 1)) {
        int sb = __builtin_amdgcn_readfirstlane(s);
        int2 e0 = csr[sb];
        int4 v0 = cfW1[(size_t)(e0.x & 1023) * 32 + sl];
        float n = (g == 0) ? __int_as_float(e0.y) : 0.0f;
        acc8(esum, v0, n);
        ++s;
    }
    // pipelined main: 4 pairs (8 edges) per iter; prefetch next csr batch
    int4 ee[4];
    if (s + 8 <= a1) {
        int sb = __builtin_amdgcn_readfirstlane(s);
        #pragma unroll
        for (int u = 0; u < 4; ++u) ee[u] = *(const int4*)(csr + sb + 2 * u);
    }
    while (s + 8 <= a1) {
        int4 ce[4];
        #pragma unroll
        for (int u = 0; u < 4; ++u) ce[u] = ee[u];
        int sn = s + 8;
        if (sn + 8 <= a1) {           // prefetch next batch (SGPR, overlaps gathers)
            int sb2 = __builtin_amdgcn_readfirstlane(sn);
            #pragma unroll
            for (int u = 0; u < 4; ++u) ee[u] = *(const int4*)(csr + sb2 + 2 * u);
        }
        int4 v[4]; float n[4];
        #pragma unroll
        for (int u = 0; u < 4; ++u) {
            int ex = g ? ce[u].z : ce[u].x;
            int ey = g ? ce[u].w : ce[u].y;
            n[u] = __int_as_float(ey);
            v[u] = cfW1[(size_t)(ex & 1023) * 32 + sl];
        }
        #pragma unroll
        for (int u = 0; u < 4; ++u) acc8(esum, v[u], n[u]);
        s = sn;
    }
    // pair tail
    for (; s + 2 <= a1; s += 2) {
        int sb = __builtin_amdgcn_readfirstlane(s);
        int4 e2 = *(const int4*)(csr + sb);
        int ex = g ? e2.z : e2.x;
        int ey = g ? e2.w : e2.y;
        int4 v0 = cfW1[(size_t)(ex & 1023) * 32 + sl];
        acc8(esum, v0, __int_as_float(ey));
    }
    // single tail
    if (s < a1) {
        int sb = __builtin_amdgcn_readfirstlane(s);
        int2 e0 = csr[sb];
        int4 v0 = cfW1[(size_t)(e0.x & 1023) * 32 + sl];
        float n = (g == 0) ? __int_as_float(e0.y) : 0.0f;
        acc8(esum, v0, n);
    }
    // combine the two half-wave partial sums
    #pragma unroll
    for (int k = 0; k < 8; ++k) esum[k] += __shfl_xor(esum[k], 32, 64);

    float dd = d * d;
    float2 s0 = __half22float2(*(__half2*)&sp.x);
    float2 s1 = __half22float2(*(__half2*)&sp.y);
    float2 s2 = __half22float2(*(__half2*)&sp.z);
    float2 s3 = __half22float2(*(__half2*)&sp.w);
    float4 bb0 = b1f4[2 * sl];
    float4 bb1 = b1f4[2 * sl + 1];
    float r[8];
    r[0] = bb0.x + s0.x * dd + d * esum[0];
    r[1] = bb0.y + s0.y * dd + d * esum[1];
    r[2] = bb0.z + s1.x * dd + d * esum[2];
    r[3] = bb0.w + s1.y * dd + d * esum[3];
    r[4] = bb1.x + s2.x * dd + d * esum[4];
    r[5] = bb1.y + s2.y * dd + d * esum[5];
    r[6] = bb1.z + s3.x * dd + d * esum[6];
    r[7] = bb1.w + s3.y * dd + d * esum[7];
    #pragma unroll
    for (int k = 0; k < 8; ++k) r[k] = r[k] > 0.f ? r[k] : 0.f;
    float2 p0 = {r[0], r[1]}, p1 = {r[2], r[3]}, p2 = {r[4], r[5]}, p3 = {r[6], r[7]};
    __half2 h0 = __float22half2_rn(p0);
    __half2 h1v = __float22half2_rn(p1);
    __half2 h2 = __float22half2_rn(p2);
    __half2 h3 = __float22half2_rn(p3);
    int4 outv;
    outv.x = *(int*)&h0;
    outv.y = *(int*)&h1v;
    outv.z = *(int*)&h2;
    outv.w = *(int*)&h3;
    if (lane < 32) h1[(size_t)c * 32 + sl] = outv;
}

// ---------------- GEMM2 via MFMA: h1 [N,256] fp16 @ W2 -> xw2h fp16 ---------

__global__ void k_gemm2(const _Float16* __restrict__ h1, const _Float16* __restrict__ W2T,
                        __half* __restrict__ xw2h) {
    int wave = threadIdx.x >> 6;
    int lane = threadIdx.x & 63;
    int quad = lane >> 4;
    int n    = lane & 15;
    int tm   = blockIdx.x * 4 + wave;                  // 16-row tile index
    const _Float16* arow = h1 + (size_t)(tm * 16 + n) * H_DIM;
    half8 a[8];
    #pragma unroll
    for (int kt = 0; kt < 8; ++kt)
        a[kt] = *(const half8*)(arow + kt * 32 + quad * 8);
    #pragma unroll
    for (int nt = 0; nt < 8; ++nt) {
        floatx4 acc = {0.f, 0.f, 0.f, 0.f};
        const _Float16* brow = W2T + (size_t)(nt * 16 + n) * H_DIM;
        #pragma unroll
        for (int kt = 0; kt < 8; ++kt) {
            half8 b = *(const half8*)(brow + kt * 32 + quad * 8);
            acc = __builtin_amdgcn_mfma_f32_16x16x32_f16(a[kt], b, acc, 0, 0, 0);
        }
        #pragma unroll
        for (int r = 0; r < 4; ++r) {
            int rowi = tm * 16 + quad * 4 + r;
            xw2h[(size_t)rowi * O_DIM + nt * 16 + n] = __float2half(acc[r]);
        }
    }
}

// ---------------- layer-2 agg + relu + LDS-reduced pool (R1-exact) ----------

__global__ void k_agg2_pool(const int4* __restrict__ xw2h, const float* __restrict__ b2,
                            const float* __restrict__ dis, const int* __restrict__ offs,
                            const int2* __restrict__ csr, const int* __restrict__ batch,
                            float* __restrict__ pool) {
    __shared__ float red[4][128];
    __shared__ int bgs[4];
    int wave = threadIdx.x >> 6;
    int lane = threadIdx.x & 63;
    int grp  = lane >> 4;        // which edge of the quad
    int sl   = lane & 15;        // int4 slot within the 128-half row
    int c = blockIdx.x * 4 + wave;
    float d = dis[c];
    int4 sp = xw2h[(size_t)c * 16 + sl];
    float esum[8] = {0.f, 0.f, 0.f, 0.f, 0.f, 0.f, 0.f, 0.f};
    int s0 = offs[c], s1 = offs[c + 1];
    int s = s0;
    // main: 4 quads (16 edges) per batch, 4 int4 gathers in flight
    for (; s + 16 <= s1; s += 16) {
        int sb = __builtin_amdgcn_readfirstlane(s);
        int2 e[4];
        #pragma unroll
        for (int u = 0; u < 4; ++u) e[u] = csr[sb + 4 * u + grp];
        int4 v[4];
        #pragma unroll
        for (int u = 0; u < 4; ++u)
            v[u] = xw2h[(size_t)(((unsigned)e[u].x) >> 10) * 16 + sl];
        #pragma unroll
        for (int u = 0; u < 4; ++u) acc8(esum, v[u], __int_as_float(e[u].y));
    }
    // quad tail
    for (; s + 4 <= s1; s += 4) {
        int sb = __builtin_amdgcn_readfirstlane(s);
        int2 e0 = csr[sb + grp];
        int4 v0 = xw2h[(size_t)(((unsigned)e0.x) >> 10) * 16 + sl];
        acc8(esum, v0, __int_as_float(e0.y));
    }
    // remainder 0..3 edges: clamp index, zero weight for invalid lanes
    if (s < s1) {
        int sb = __builtin_amdgcn_readfirstlane(s);
        int idx = sb + grp;
        int idc = idx < s1 ? idx : s1 - 1;
        int2 e0 = csr[idc];
        int4 v0 = xw2h[(size_t)(((unsigned)e0.x) >> 10) * 16 + sl];
        float n = (idx < s1) ? __int_as_float(e0.y) : 0.0f;
        acc8(esum, v0, n);
    }
    // combine the 4 lane-group partial sums
    #pragma unroll
    for (int k = 0; k < 8; ++k) {
        esum[k] += __shfl_xor(esum[k], 16, 64);
        esum[k] += __shfl_xor(esum[k], 32, 64);
    }
    float dd = d * d;
    float2 f0 = __half22float2(*(__half2*)&sp.x);
    float2 f1 = __half22float2(*(__half2*)&sp.y);
    float2 f2 = __half22float2(*(__half2*)&sp.z);
    float2 f3 = __half22float2(*(__half2*)&sp.w);
    float4 bb0 = ((const float4*)b2)[2 * sl];
    float4 bb1 = ((const float4*)b2)[2 * sl + 1];
    float acc[8];
    acc[0] = bb0.x + f0.x * dd + d * esum[0];
    acc[1] = bb0.y + f0.y * dd + d * esum[1];
    acc[2] = bb0.z + f1.x * dd + d * esum[2];
    acc[3] = bb0.w + f1.y * dd + d * esum[3];
    acc[4] = bb1.x + f2.x * dd + d * esum[4];
    acc[5] = bb1.y + f2.y * dd + d * esum[5];
    acc[6] = bb1.z + f3.x * dd + d * esum[6];
    acc[7] = bb1.w + f3.y * dd + d * esum[7];
    #pragma unroll
    for (int k = 0; k < 8; ++k) acc[k] = acc[k] > 0.f ? acc[k] : 0.f;
    if (grp == 0) {
        #pragma unroll
        for (int k = 0; k < 8; ++k) red[wave][8 * sl + k] = acc[k];
    }
    if (lane == 0) bgs[wave] = batch[c];
    __syncthreads();
    if (wave == 0) {
        float2 a;
        a.x = red[0][2 * lane];
        a.y = red[0][2 * lane + 1];
        int cg = bgs[0];
        #pragma unroll
        for (int w = 1; w < 4; ++w) {
            int g = bgs[w];
            float2 r;
            r.x = red[w][2 * lane];
            r.y = red[w][2 * lane + 1];
            if (g == cg) { a.x += r.x; a.y += r.y; }
            else {
                atomicAdd(&pool[cg * O_DIM + 2 * lane], a.x);
                atomicAdd(&pool[cg * O_DIM + 2 * lane + 1], a.y);
                a = r; cg = g;
            }
        }
        atomicAdd(&pool[cg * O_DIM + 2 * lane], a.x);
        atomicAdd(&pool[cg * O_DIM + 2 * lane + 1], a.y);
    }
}

__global__ void k_final(const float* __restrict__ pool, const float* __restrict__ cnt,
                        float* __restrict__ out) {
    int t = blockIdx.x * blockDim.x + threadIdx.x;
    if (t < N_GRAPH * O_DIM) {
        int g = t / O_DIM;
        out[t] = pool[t] / fmaxf(cnt[g], 1.0f);
    }
}

// ---------------- launch ----------------

extern "C" void kernel_launch(void* const* d_in, const int* in_sizes, int n_in,
                              void* d_out, int out_size, void* d_ws, size_t ws_size,
                              hipStream_t stream) {
    const float* cf   = (const float*)d_in[0];   // [V,128]
    const float* W1   = (const float*)d_in[1];   // [128,256]
    const float* b1   = (const float*)d_in[2];   // [256]
    const float* W2   = (const float*)d_in[3];   // [256,128]
    const float* b2   = (const float*)d_in[4];   // [128]
    const float* ew   = (const float*)d_in[5];   // [E]
    const int*   nidx = (const int*)d_in[6];     // [N]
    const int*   eidx = (const int*)d_in[7];     // [2,E]
    const int*   bidx = (const int*)d_in[8];     // [N]
    float* out = (float*)d_out;

    const int* row = eidx;            // source
    const int* col = eidx + N_EDGES;  // target

    // workspace layout (bytes)
    char* ws = (char*)d_ws;
    size_t off = 0;
    int*   hist  = (int*)  (ws + off); off += (size_t)N_NODES * 4;          // 256K
    int*   hoffs = (int*)  (ws + off); off += (size_t)N_NODES * 4;          // 256K
    int*   bsum  = (int*)  (ws + off); off += 4096;
    float* dis   = (float*)(ws + off); off += (size_t)N_NODES * 4;          // 256K
    int*   offs  = (int*)  (ws + off); off += (size_t)(N_NODES + 16) * 4;   // 256K
    int2*  csr   = (int2*) (ws + off); off += (size_t)N_EDGES * 8;          // 16M
    float* pool  = (float*)(ws + off); off += (size_t)(N_GRAPH * O_DIM + N_GRAPH) * 4;
    __half* cfW1 = (__half*)(ws + off); off += (size_t)V_SIZE * H_DIM * 2;  // 512K
    _Float16* W2T = (_Float16*)(ws + off); off += (size_t)O_DIM * H_DIM * 2; // 64K
    off = (off + 255) & ~(size_t)255;
    int2*  part  = (int2*) (ws + off); off += (size_t)N_EDGES * 8;          // 16M
    __half* h1   = (__half*)(ws + off);                                     // 32M
    __half* xw2h = (__half*)part;    // part dead after k_build2
    float* cntf  = pool + N_GRAPH * O_DIM;

    // 1. fused init + histogram, then partial scan (bsum stays raw)
    k_init_hist<<<512, 1024, 0, stream>>>(pool, bidx, cntf, cf, W1, cfW1, W2, W2T,
                                          col, hist);
    k_scan1<<<256, 256, 0, stream>>>(hist, hoffs, bsum);

    // 2. partition -> build1 (deg/dis/offs) -> build2 (CSR w/ nrm applied)
    //    (each does the cheap 256-wide bsum scan in its prologue)
    k_part<<<NBLK, 1024, 0, stream>>>(row, col, ew, nidx, hoffs, bsum, part);
    k_build1<<<256, 1024, 0, stream>>>(hoffs, bsum, part, dis, offs);
    k_build2<<<256, 1024, 0, stream>>>(hoffs, bsum, part, dis, offs, csr);

    // 3. layer 1: gather-aggregate from the 512 KB cfW1 table -> h1 (fp16)
    k_agg1<<<N_NODES / 4, 256, 0, stream>>>((const int4*)cfW1, nidx, dis, offs, csr,
                                            (const float4*)b1, (int4*)h1);

    // 4. layer 2: MFMA GEMM2, then aggregate + relu + LDS-reduced pool
    k_gemm2<<<N_NODES / 64, 256, 0, stream>>>((const _Float16*)h1, W2T, xw2h);
    k_agg2_pool<<<N_NODES / 4, 256, 0, stream>>>((const int4*)xw2h, b2, dis, offs, csr,
                                                 bidx, pool);

    // 5. final divide
    k_final<<<(N_GRAPH * O_DIM + 255) / 256, 256, 0, stream>>>(pool, cntf, out);
}